// Round 1
// baseline (10971.570 us; speedup 1.0000x reference)
//
#include <hip/hip_runtime.h>
#include <math.h>

#define KK 55
#define KP 56       // padded k row (zero in col 55)
#define XW 112      // padded x row stride (cols -28..83)
#define XH 110      // padded rows (rows -27..82)
#define DIM 192
#define FEMB 32
#define FORD 64
#define HW 56
#define NT 3025     // 55*55
#define KPAD 3080   // 55*56

// ---- Stage A: h2T[o][t] = sin(f2*(W2 @ sin(f1*(W1 @ z + b1)) + b2)) ----
__global__ __launch_bounds__(FORD) void mlp_kernel(
    const float* __restrict__ z,
    const float* __restrict__ W1, const float* __restrict__ b1, const float* __restrict__ f1,
    const float* __restrict__ W2, const float* __restrict__ b2, const float* __restrict__ f2,
    float* __restrict__ h2T) {
    const int t = blockIdx.x;      // 0..3024
    const int o = threadIdx.x;     // 0..63
    __shared__ float h1s[FORD];
    float acc = b1[o];
    for (int c = 0; c < FEMB; ++c) acc += W1[o*FEMB + c] * z[c*NT + t];
    h1s[o] = sinf(f1[o] * acc);
    __syncthreads();
    float acc2 = b2[o];
    for (int oo = 0; oo < FORD; ++oo) acc2 += W2[o*FORD + oo] * h1s[oo];
    h2T[o*NT + t] = sinf(f2[o] * acc2);
}

// ---- Stage B: kpad[c][p][q] = (W3[c]·h2[:,p*55+q]) * (exp(-d*|delta_c|)+shift_c) ----
__global__ __launch_bounds__(256) void kgen_kernel(
    const float* __restrict__ h2T, const float* __restrict__ W3,
    const float* __restrict__ deltas, const float* __restrict__ shift,
    const float* __restrict__ dmap, float* __restrict__ kpad) {
    const int idx = blockIdx.x * 256 + threadIdx.x;
    if (idx >= DIM * KPAD) return;
    const int c = idx / KPAD;
    const int r = idx - c * KPAD;
    const int p = r / KP;
    const int q = r - p * KP;
    if (q == KK) { kpad[idx] = 0.0f; return; }   // zero pad column
    const int t = p * KK + q;
    float acc = 0.0f;
    #pragma unroll
    for (int o = 0; o < FORD; ++o) acc += W3[c*FORD + o] * h2T[o*NT + t];
    const float a   = fabsf(deltas[c]);
    const float dec = expf(-dmap[t] * a);
    kpad[idx] = acc * (dec + shift[c]);
}

// ---- Stage C: depthwise 55x55 "same" conv + bias*x ----
// One block per (c,b). LDS: zero-padded x plane (110x112) + padded kernel (55x56).
__global__ __launch_bounds__(256) void conv_kernel(
    const float* __restrict__ x, const float* __restrict__ kpad,
    const float* __restrict__ bias, float* __restrict__ out) {
    __shared__ float lx[XH * XW];   // 12320 floats
    __shared__ float lk[KPAD];      // 3080 floats

    const int c = blockIdx.x;
    const int b = blockIdx.y;
    const int tid = threadIdx.x;

    for (int i = tid; i < XH * XW; i += 256) lx[i] = 0.0f;
    {
        const float* kc = kpad + c * KPAD;
        for (int i = tid; i < KPAD; i += 256) lk[i] = kc[i];
    }
    __syncthreads();   // zeros must land before interior fill (different writers)
    {
        const float* xp = x + (size_t)(b * DIM + c) * (HW * HW);
        for (int i = tid; i < HW * HW; i += 256) {
            const int rr = i / HW;
            const int cc = i - rr * HW;
            lx[(rr + 27) * XW + cc + 28] = xp[i];
        }
    }
    __syncthreads();

    const float bc = bias[c];
    float* op = out + (size_t)(b * DIM + c) * (HW * HW);

    const int jt    = tid & 15;          // 16 j-tiles of 4 (14 real)
    const int j0    = 4 * (jt < 14 ? jt : 13);   // clamp waste lanes in-bounds
    const int irow  = tid >> 4;          // 0..15

    for (int ib = 0; ib < 64; ib += 16) {
        const int ireal = ib + irow;
        const int i = ireal < HW ? ireal : HW - 1;   // clamp waste rows in-bounds
        float a0 = 0.f, a1 = 0.f, a2 = 0.f, a3 = 0.f;

        for (int p = 0; p < KK; ++p) {
            const int rb = (i + 54 - p) * XW + j0;           // window base (4-aligned)
            const float4* __restrict__ xr  = (const float4*)(lx + rb);
            const float4* __restrict__ kr4 = (const float4*)(lk + p * KP);
            float4 A = xr[0];
            #pragma unroll
            for (int gg = 0; gg < 7; ++gg) {
                // group g = 2*gg  (taps q' = 55-8gg .. 52-8gg)
                const float4 Bv = xr[2*gg + 1];
                const float4 kv = kr4[13 - 2*gg];
                a0 = fmaf(kv.w, A.x, a0); a0 = fmaf(kv.z, A.y, a0); a0 = fmaf(kv.y, A.z, a0); a0 = fmaf(kv.x, A.w, a0);
                a1 = fmaf(kv.w, A.y, a1); a1 = fmaf(kv.z, A.z, a1); a1 = fmaf(kv.y, A.w, a1); a1 = fmaf(kv.x, Bv.x, a1);
                a2 = fmaf(kv.w, A.z, a2); a2 = fmaf(kv.z, A.w, a2); a2 = fmaf(kv.y, Bv.x, a2); a2 = fmaf(kv.x, Bv.y, a2);
                a3 = fmaf(kv.w, A.w, a3); a3 = fmaf(kv.z, Bv.x, a3); a3 = fmaf(kv.y, Bv.y, a3); a3 = fmaf(kv.x, Bv.z, a3);
                // group g = 2*gg+1
                const float4 A2  = xr[2*gg + 2];
                const float4 kv2 = kr4[12 - 2*gg];
                a0 = fmaf(kv2.w, Bv.x, a0); a0 = fmaf(kv2.z, Bv.y, a0); a0 = fmaf(kv2.y, Bv.z, a0); a0 = fmaf(kv2.x, Bv.w, a0);
                a1 = fmaf(kv2.w, Bv.y, a1); a1 = fmaf(kv2.z, Bv.z, a1); a1 = fmaf(kv2.y, Bv.w, a1); a1 = fmaf(kv2.x, A2.x, a1);
                a2 = fmaf(kv2.w, Bv.z, a2); a2 = fmaf(kv2.z, Bv.w, a2); a2 = fmaf(kv2.y, A2.x, a2); a2 = fmaf(kv2.x, A2.y, a2);
                a3 = fmaf(kv2.w, Bv.w, a3); a3 = fmaf(kv2.z, A2.x, a3); a3 = fmaf(kv2.y, A2.y, a3); a3 = fmaf(kv2.x, A2.z, a3);
                A = A2;
            }
        }

        if (ireal < HW && jt < 14) {
            const int ctr = (i + 27) * XW + j0 + 28;
            float4 res;
            res.x = a0 + bc * lx[ctr + 0];
            res.y = a1 + bc * lx[ctr + 1];
            res.z = a2 + bc * lx[ctr + 2];
            res.w = a3 + bc * lx[ctr + 3];
            *(float4*)(op + i * HW + j0) = res;
        }
    }
}

extern "C" void kernel_launch(void* const* d_in, const int* in_sizes, int n_in,
                              void* d_out, int out_size, void* d_ws, size_t ws_size,
                              hipStream_t stream) {
    const float* x      = (const float*)d_in[0];
    const float* z      = (const float*)d_in[1];
    const float* W1     = (const float*)d_in[2];
    const float* b1     = (const float*)d_in[3];
    const float* f1     = (const float*)d_in[4];
    const float* W2     = (const float*)d_in[5];
    const float* b2     = (const float*)d_in[6];
    const float* f2     = (const float*)d_in[7];
    const float* W3     = (const float*)d_in[8];
    const float* deltas = (const float*)d_in[9];
    const float* shift  = (const float*)d_in[10];
    const float* bias   = (const float*)d_in[11];
    const float* dmap   = (const float*)d_in[12];
    float* out = (float*)d_out;

    float* h2T  = (float*)d_ws;            // 64*3025 floats  (~0.77 MB)
    float* kpad = h2T + FORD * NT;         // 192*3080 floats (~2.4 MB)

    mlp_kernel<<<NT, FORD, 0, stream>>>(z, W1, b1, f1, W2, b2, f2, h2T);
    kgen_kernel<<<(DIM * KPAD + 255) / 256, 256, 0, stream>>>(h2T, W3, deltas, shift, dmap, kpad);
    conv_kernel<<<dim3(DIM, 64), 256, 0, stream>>>(x, kpad, bias, out);
}

// Round 2
// 2392.770 us; speedup vs baseline: 4.5853x; 4.5853x over previous
//
#include <hip/hip_runtime.h>
#include <math.h>

#define DIM 192
#define FEMB 32
#define FORD 64
#define HW 56
#define KK 55
#define NT 3025      // 55*55
#define KROWH 112    // halfs per k row: ke[56] | ko[56]
#define XROWH 120    // halfs per padded x row (cols -28..91)
#define XROWS 110    // padded rows (-27..82)

typedef _Float16 h2 __attribute__((ext_vector_type(2)));
typedef _Float16 h4 __attribute__((ext_vector_type(4)));
typedef _Float16 h8 __attribute__((ext_vector_type(8)));

#if __has_builtin(__builtin_amdgcn_fdot2)
#define FDOT2(a, b, c) __builtin_amdgcn_fdot2((a), (b), (c), false)
#else
#define FDOT2(a, b, c) ((c) + (float)(a).x * (float)(b).x + (float)(a).y * (float)(b).y)
#endif

__device__ __forceinline__ h2 mk2(_Float16 a, _Float16 b) { h2 r; r.x = a; r.y = b; return r; }

// ---- Stage A: h2T[o][t] = sin(f2*(W2 @ sin(f1*(W1 @ z + b1)) + b2)) ----
__global__ __launch_bounds__(FORD) void mlp_kernel(
    const float* __restrict__ z,
    const float* __restrict__ W1, const float* __restrict__ b1, const float* __restrict__ f1,
    const float* __restrict__ W2, const float* __restrict__ b2, const float* __restrict__ f2,
    float* __restrict__ h2T) {
    const int t = blockIdx.x;      // 0..3024
    const int o = threadIdx.x;     // 0..63
    __shared__ float h1s[FORD];
    float acc = b1[o];
    for (int c = 0; c < FEMB; ++c) acc += W1[o*FEMB + c] * z[c*NT + t];
    h1s[o] = sinf(f1[o] * acc);
    __syncthreads();
    float acc2 = b2[o];
    for (int oo = 0; oo < FORD; ++oo) acc2 += W2[o*FORD + oo] * h1s[oo];
    h2T[o*NT + t] = sinf(f2[o] * acc2);
}

// ---- Stage B: flipped f16 kernel, even-pair copy [0..55] and odd-pair (shift-1) copy [56..111]
// kflip[p][w] = k[p][55-w] (w=0 and w=56 are zero pads).
__global__ __launch_bounds__(256) void kgen_kernel(
    const float* __restrict__ h2T, const float* __restrict__ W3,
    const float* __restrict__ deltas, const float* __restrict__ shift,
    const float* __restrict__ dmap, _Float16* __restrict__ kf) {
    const int idx = blockIdx.x * 256 + threadIdx.x;
    if (idx >= DIM * KK * 56) return;
    const int c = idx / (KK * 56);
    const int r = idx - c * (KK * 56);
    const int p = r / 56;
    const int q = r - p * 56;
    _Float16* row = kf + (size_t)c * KK * KROWH + p * KROWH;
    if (q == KK) { row[0] = (_Float16)0.f; row[111] = (_Float16)0.f; return; }
    const int t = p * KK + q;
    float acc = 0.0f;
    #pragma unroll
    for (int o = 0; o < FORD; ++o) acc += W3[c*FORD + o] * h2T[o*NT + t];
    acc *= (expf(-dmap[t] * fabsf(deltas[c])) + shift[c]);
    row[55 - q]  = (_Float16)acc;   // kflip[55-q]  (even-pair copy)
    row[110 - q] = (_Float16)acc;   // shifted copy: half 56+s with s=54-q
}

// ---- Stage C: depthwise 55x55 conv via v_dot2_f32_f16 + bias*x ----
// 128 threads: jt = tid&1 (j0 = 32*jt), rt = tid>>1 (row, clamped).
// out[i][j] = sum_p sum_w kflip[p][w] * xpad[i+54-p][j+w]
__global__ __launch_bounds__(128) void conv_kernel(
    const float* __restrict__ x, const _Float16* __restrict__ kf,
    const float* __restrict__ bias, float* __restrict__ out) {
    __shared__ _Float16 lx[XROWS * XROWH];   // 26400 B
    __shared__ _Float16 lk[KK * KROWH];      // 12320 B

    const int c = blockIdx.x;
    const int b = blockIdx.y;
    const int tid = threadIdx.x;

    // zero x buffer (pads)
    {
        int4* z4 = (int4*)lx;
        #pragma unroll 1
        for (int i = tid; i < XROWS * XROWH * 2 / 16; i += 128) z4[i] = int4{0,0,0,0};
    }
    // stage kernel rows (already packed by kgen)
    {
        const int4* kg = (const int4*)(kf + (size_t)c * KK * KROWH);
        int4* lk4 = (int4*)lk;
        #pragma unroll 1
        for (int i = tid; i < KK * KROWH * 2 / 16; i += 128) lk4[i] = kg[i];
    }
    __syncthreads();
    // fill x interior (f32 -> f16)
    {
        const float4* xp = (const float4*)(x + (size_t)(b * DIM + c) * (HW * HW));
        #pragma unroll 1
        for (int i2 = tid; i2 < HW * 14; i2 += 128) {
            const int rr = i2 / 14;
            const int cc = (i2 - rr * 14) * 4;
            float4 v = xp[i2];
            h4 t; t[0] = (_Float16)v.x; t[1] = (_Float16)v.y; t[2] = (_Float16)v.z; t[3] = (_Float16)v.w;
            *(h4*)(lx + (rr + 27) * XROWH + 28 + cc) = t;
        }
    }
    __syncthreads();

    const int jt = tid & 1;
    const int rt = tid >> 1;               // 0..63; rows >=56 are waste (clamped)
    const int irow = rt < HW ? rt : HW - 1;
    const int xoff = 32 * jt;              // half offset of X window base

    float acc[32];
    #pragma unroll
    for (int s = 0; s < 32; ++s) acc[s] = 0.0f;

    #pragma unroll 1
    for (int p = 0; p < KK; ++p) {
        const _Float16* xr = lx + (irow + 54 - p) * XROWH + xoff;
        const _Float16* krow = lk + p * KROWH;

        h2 X[44];
        #pragma unroll
        for (int s = 0; s < 11; ++s) {
            h8 t = *(const h8*)(xr + 8 * s);
            X[4*s+0] = mk2(t[0], t[1]);
            X[4*s+1] = mk2(t[2], t[3]);
            X[4*s+2] = mk2(t[4], t[5]);
            X[4*s+3] = mk2(t[6], t[7]);
        }
        #pragma unroll
        for (int mc = 0; mc < 7; ++mc) {
            h8 te = *(const h8*)(krow + 8 * mc);        // even pairs
            h8 to = *(const h8*)(krow + 56 + 8 * mc);   // odd  pairs
            #pragma unroll
            for (int m4 = 0; m4 < 4; ++m4) {
                const h2 ke = mk2(te[2*m4], te[2*m4+1]);
                const h2 ko = mk2(to[2*m4], to[2*m4+1]);
                const int m = 4 * mc + m4;
                #pragma unroll
                for (int v = 0; v < 16; ++v) {
                    acc[2*v]   = FDOT2(ke, X[v + m],     acc[2*v]);
                    acc[2*v+1] = FDOT2(ko, X[v + m + 1], acc[2*v+1]);
                }
            }
        }
    }

    if (rt < HW) {
        const float bc = bias[c];
        float* op = out + (size_t)(b * DIM + c) * (HW * HW) + rt * HW + 32 * jt;
        const _Float16* brow = lx + (rt + 27) * XROWH + 28 + 32 * jt;
        #pragma unroll
        for (int s = 0; s < 8; ++s) {
            if (32 * jt + 4 * s < HW) {     // jt=0: all 8; jt=1: first 6
                float4 r;
                r.x = acc[4*s+0] + bc * (float)brow[4*s+0];
                r.y = acc[4*s+1] + bc * (float)brow[4*s+1];
                r.z = acc[4*s+2] + bc * (float)brow[4*s+2];
                r.w = acc[4*s+3] + bc * (float)brow[4*s+3];
                ((float4*)op)[s] = r;
            }
        }
    }
}

extern "C" void kernel_launch(void* const* d_in, const int* in_sizes, int n_in,
                              void* d_out, int out_size, void* d_ws, size_t ws_size,
                              hipStream_t stream) {
    const float* x      = (const float*)d_in[0];
    const float* z      = (const float*)d_in[1];
    const float* W1     = (const float*)d_in[2];
    const float* b1     = (const float*)d_in[3];
    const float* f1     = (const float*)d_in[4];
    const float* W2     = (const float*)d_in[5];
    const float* b2     = (const float*)d_in[6];
    const float* f2     = (const float*)d_in[7];
    const float* W3     = (const float*)d_in[8];
    const float* deltas = (const float*)d_in[9];
    const float* shift  = (const float*)d_in[10];
    const float* bias   = (const float*)d_in[11];
    const float* dmap   = (const float*)d_in[12];
    float* out = (float*)d_out;

    float* h2T = (float*)d_ws;                       // 64*3025 f32 = 774400 B
    _Float16* kf = (_Float16*)((char*)d_ws + 774400); // 192*55*112 f16 = 2365440 B

    mlp_kernel<<<NT, FORD, 0, stream>>>(z, W1, b1, f1, W2, b2, f2, h2T);
    kgen_kernel<<<(DIM * KK * 56 + 255) / 256, 256, 0, stream>>>(h2T, W3, deltas, shift, dmap, kf);
    conv_kernel<<<dim3(DIM, 64), 128, 0, stream>>>(x, kf, bias, out);
}